// Round 6
// baseline (58.168 us; speedup 1.0000x reference)
//
#include <hip/hip_runtime.h>
#include <hip/hip_bf16.h>

// B=8192, S=200, E=8, H1=64, H2=32
// att_in = [q, h, q-h, q*h] (32) -> relu(@W1[32,64]+b1) -> relu(@W2[64,32]+b2)
// score = @W3[32,1]+b3 ; mask s<len ; out[b,:] = sum_s score*hist[b,s,:]
// Transposed chain (h1^T = W1^T att^T, h2^T = W2^T relu(h1)^T) so h2 of position c
// stays in position-c lanes. Row split across 2 waves; no hard LDS drains.
#define BB 8192
#define SS 200

typedef __attribute__((ext_vector_type(8))) short short8;   // bf16x8 MFMA frag
typedef __attribute__((ext_vector_type(4))) float f32x4;    // fp32x4 MFMA acc

__device__ __forceinline__ unsigned short f2bf(float f) {
    union { float f; unsigned int u; } v; v.f = f;
    unsigned int r = v.u + 0x7FFFu + ((v.u >> 16) & 1u);    // RNE
    return (unsigned short)(r >> 16);
}
// pack 2 fp32 -> 1 u32 of 2 bf16 (v_cvt_pk_bf16_f32)
__device__ __forceinline__ unsigned int packbf2(float a, float b) {
    union { __hip_bfloat162 h; unsigned int u; } v;
    v.h = __float22bfloat162_rn(make_float2(a, b));
    return v.u;
}

// ---- prep: pack W1 [32,64], W2 [64,32] into per-lane bf16 A-frags (transposed use) ----
// wsW1[(n*64+l)*8+j]        = W1[8g+j][16n+c]      (stage-1' A = W1^T tile n)
// wsW2[((kc*2+n)*64+l)*8+j] = W2[32kc+8g+j][16n+c] (stage-2' A = W2^T tile n, k-chunk kc)
__global__ void prep_kernel(const float* __restrict__ W1, const float* __restrict__ W2,
                            unsigned short* __restrict__ wsW1,
                            unsigned short* __restrict__ wsW2) {
    int t = threadIdx.x;             // 0..255
    int l = t & 63;
    int g = l >> 4, c = l & 15;
    {
        int n = t >> 6;              // 0..3
#pragma unroll
        for (int j = 0; j < 8; ++j)
            wsW1[(n * 64 + l) * 8 + j] = f2bf(W1[(8 * g + j) * 64 + 16 * n + c]);
    }
    {
        int kc = t >> 7, n = (t >> 6) & 1;
#pragma unroll
        for (int j = 0; j < 8; ++j)
            wsW2[((kc * 2 + n) * 64 + l) * 8 + j] = f2bf(W2[(32 * kc + 8 * g + j) * 32 + 16 * n + c]);
    }
}

// ---- main: 4 waves/block = 2 rows x 2 half-row waves ----
__global__ __launch_bounds__(256)
void din3_kernel(const float* __restrict__ query,       // [B,1,8]
                 const float* __restrict__ hist,        // [B,200,8]
                 const int* __restrict__ hlen,          // [B] int32
                 const unsigned short* __restrict__ wsW1,
                 const unsigned short* __restrict__ wsW2,
                 const float* __restrict__ b1,          // [64]
                 const float* __restrict__ b2,          // [32]
                 const float* __restrict__ W3,          // [32]
                 const float* __restrict__ b3,          // [1]
                 float* __restrict__ out)               // [B,1,8]
{
    const int tid  = threadIdx.x;
    const int wave = tid >> 6;
    const int l    = tid & 63;
    const int g    = l >> 4;     // k-block group
    const int c    = l & 15;     // position-within-subtile
    const int half = wave & 1;   // which half of the row this wave owns
    const int brow = blockIdx.x * 2 + (wave >> 1);

    __shared__ unsigned short lds[4][2][1024];   // per-wave h1 dbuf, 16B-slot XOR swizzle
    __shared__ float outbuf[4][8];

    const int len = hlen[brow];

    // ---- one-time per-row setup ----
    const float4* qp = reinterpret_cast<const float4*>(query + (size_t)brow * 8);
    float4 qa = qp[0], qb = qp[1];
    float q[8] = {qa.x, qa.y, qa.z, qa.w, qb.x, qb.y, qb.z, qb.w};

    // att value for this lane's k-block: v = alpha*q + (beta + gamma*q)*h
    const float alpha = (g == 0 || g == 2) ? 1.0f : 0.0f;
    const float beta  = (g == 1) ? 1.0f : ((g == 2) ? -1.0f : 0.0f);
    const float gamma = (g == 3) ? 1.0f : 0.0f;
    float aq[8], bcv[8];
#pragma unroll
    for (int j = 0; j < 8; ++j) { aq[j] = alpha * q[j]; bcv[j] = beta + gamma * q[j]; }

    short8 w1f[4];
#pragma unroll
    for (int n = 0; n < 4; ++n)
        w1f[n] = *reinterpret_cast<const short8*>(wsW1 + (n * 64 + l) * 8);
    short8 w2tf[2][2];
#pragma unroll
    for (int kc = 0; kc < 2; ++kc)
#pragma unroll
        for (int n2 = 0; n2 < 2; ++n2)
            w2tf[kc][n2] = *reinterpret_cast<const short8*>(wsW2 + ((kc * 2 + n2) * 64 + l) * 8);

    f32x4 b1c[4];
#pragma unroll
    for (int n = 0; n < 4; ++n)
        b1c[n] = *reinterpret_cast<const f32x4*>(b1 + 16 * n + 4 * g);
    f32x4 b2c[2], W3v[2];
#pragma unroll
    for (int n2 = 0; n2 < 2; ++n2) {
        b2c[n2] = *reinterpret_cast<const f32x4*>(b2 + 16 * n2 + 4 * g);
        W3v[n2] = *reinterpret_cast<const f32x4*>(W3 + 16 * n2 + 4 * g);
    }
    const float b3s = b3[0];

    // LDS offsets (ushort units):
    // write n: c*64 + ((2n + (g>>1)) ^ (c&7))*8 + (g&1)*4   (ds_write_b64)
    // read kc: c*64 + ((4kc + g) ^ (c&7))*8                 (ds_read_b128)
    int woff[4], roff[2];
#pragma unroll
    for (int n = 0; n < 4; ++n)
        woff[n] = c * 64 + (((2 * n + (g >> 1)) ^ (c & 7)) << 3) + ((g & 1) << 2);
#pragma unroll
    for (int kc = 0; kc < 2; ++kc)
        roff[kc] = c * 64 + (((4 * kc + g) ^ (c & 7)) << 3);
    unsigned short* L0 = &lds[wave][0][0];
    unsigned short* L1 = &lds[wave][1][0];

    const float* hrow = hist + (size_t)brow * SS * 8;
    float accO[8];
#pragma unroll
    for (int e = 0; e < 8; ++e) accO[e] = 0.0f;

    // wave `half` handles subtile pairs {4it+2*half, 4it+2*half+1}
    // half=0: {0,1},{4,5},{8,9},{12,13}  (4 iters)
    // half=1: {2,3},{6,7},{10,11}        (3 iters)
    const int NIT = 4 - half;

    float hA[8], hB[8];
    {
        const int sbase = 32 * half;
        const float4* pa = reinterpret_cast<const float4*>(hrow + (size_t)min(sbase + c, SS - 1) * 8);
        const float4* pb = reinterpret_cast<const float4*>(hrow + (size_t)min(sbase + 16 + c, SS - 1) * 8);
        float4 a0 = pa[0], a1 = pa[1], b0 = pb[0], b1_ = pb[1];
        hA[0]=a0.x; hA[1]=a0.y; hA[2]=a0.z; hA[3]=a0.w; hA[4]=a1.x; hA[5]=a1.y; hA[6]=a1.z; hA[7]=a1.w;
        hB[0]=b0.x; hB[1]=b0.y; hB[2]=b0.z; hB[3]=b0.w; hB[4]=b1_.x; hB[5]=b1_.y; hB[6]=b1_.z; hB[7]=b1_.w;
    }

#pragma unroll 1
    for (int it = 0; it < NIT; ++it) {
        const int s0 = 16 * (4 * it + 2 * half);

        // ---- prefetch next pair ----
        float nA[8], nB[8];
        if (it + 1 < NIT) {
            const int ns = 16 * (4 * (it + 1) + 2 * half);
            const float4* pa = reinterpret_cast<const float4*>(hrow + (size_t)min(ns + c, SS - 1) * 8);
            const float4* pb = reinterpret_cast<const float4*>(hrow + (size_t)min(ns + 16 + c, SS - 1) * 8);
            float4 a0 = pa[0], a1 = pa[1], b0 = pb[0], b1_ = pb[1];
            nA[0]=a0.x; nA[1]=a0.y; nA[2]=a0.z; nA[3]=a0.w; nA[4]=a1.x; nA[5]=a1.y; nA[6]=a1.z; nA[7]=a1.w;
            nB[0]=b0.x; nB[1]=b0.y; nB[2]=b0.z; nB[3]=b0.w; nB[4]=b1_.x; nB[5]=b1_.y; nB[6]=b1_.z; nB[7]=b1_.w;
        }

        // ---- B-role frags (att^T) ----
        union { unsigned int u[4]; short8 s; } ufA, ufB;
#pragma unroll
        for (int m = 0; m < 4; ++m) {
            ufA.u[m] = packbf2(fmaf(bcv[2*m], hA[2*m], aq[2*m]), fmaf(bcv[2*m+1], hA[2*m+1], aq[2*m+1]));
            ufB.u[m] = packbf2(fmaf(bcv[2*m], hB[2*m], aq[2*m]), fmaf(bcv[2*m+1], hB[2*m+1], aq[2*m+1]));
        }

        // ---- stage 1': h1^T = W1^T @ att^T (bias as C-operand) ----
        f32x4 a1A[4], a1B[4];
#pragma unroll
        for (int n = 0; n < 4; ++n) {
            a1A[n] = __builtin_amdgcn_mfma_f32_16x16x32_bf16(w1f[n], ufA.s, b1c[n], 0, 0, 0);
            a1B[n] = __builtin_amdgcn_mfma_f32_16x16x32_bf16(w1f[n], ufB.s, b1c[n], 0, 0, 0);
        }

        // ---- relu + pack + swizzled b64 writes ----
#pragma unroll
        for (int n = 0; n < 4; ++n) {
            uint2 vA = make_uint2(packbf2(fmaxf(a1A[n][0], 0.f), fmaxf(a1A[n][1], 0.f)),
                                  packbf2(fmaxf(a1A[n][2], 0.f), fmaxf(a1A[n][3], 0.f)));
            uint2 vB = make_uint2(packbf2(fmaxf(a1B[n][0], 0.f), fmaxf(a1B[n][1], 0.f)),
                                  packbf2(fmaxf(a1B[n][2], 0.f), fmaxf(a1B[n][3], 0.f)));
            *reinterpret_cast<uint2*>(L0 + woff[n]) = vA;
            *reinterpret_cast<uint2*>(L1 + woff[n]) = vB;
        }

        // Same-wave LDS ops execute in order at the DS unit -> no hardware drain
        // needed; just stop the compiler from sinking writes past the reads.
        asm volatile("" ::: "memory");

        short8 hbA[2], hbB[2];
#pragma unroll
        for (int kc = 0; kc < 2; ++kc) {
            hbA[kc] = *reinterpret_cast<const short8*>(L0 + roff[kc]);
            hbB[kc] = *reinterpret_cast<const short8*>(L1 + roff[kc]);
        }

        // ---- stage 2': h2^T = W2^T @ relu(h1)^T ----
        f32x4 a2A[2], a2B[2];
#pragma unroll
        for (int n2 = 0; n2 < 2; ++n2) {
            a2A[n2] = __builtin_amdgcn_mfma_f32_16x16x32_bf16(w2tf[0][n2], hbA[0], b2c[n2], 0, 0, 0);
            a2A[n2] = __builtin_amdgcn_mfma_f32_16x16x32_bf16(w2tf[1][n2], hbA[1], a2A[n2], 0, 0, 0);
            a2B[n2] = __builtin_amdgcn_mfma_f32_16x16x32_bf16(w2tf[0][n2], hbB[0], b2c[n2], 0, 0, 0);
            a2B[n2] = __builtin_amdgcn_mfma_f32_16x16x32_bf16(w2tf[1][n2], hbB[1], a2B[n2], 0, 0, 0);
        }

        // ---- stage 3: lane-local dot with W3, 2-hop butterfly over g-copies ----
        float pA = 0.f, pB = 0.f;
#pragma unroll
        for (int n2 = 0; n2 < 2; ++n2)
#pragma unroll
            for (int r = 0; r < 4; ++r) {
                pA = fmaf(fmaxf(a2A[n2][r], 0.f), W3v[n2][r], pA);
                pB = fmaf(fmaxf(a2B[n2][r], 0.f), W3v[n2][r], pB);
            }
        pA += __shfl_xor(pA, 16); pA += __shfl_xor(pA, 32);
        pB += __shfl_xor(pB, 16); pB += __shfl_xor(pB, 32);

        float scA = (s0 + c      < len) ? (pA + b3s) : 0.0f;
        float scB = (s0 + 16 + c < len) ? (pB + b3s) : 0.0f;

        // ---- pooling (fp32 hist already in the right lanes) ----
#pragma unroll
        for (int e = 0; e < 8; ++e) {
            accO[e] = fmaf(scA, hA[e], accO[e]);
            accO[e] = fmaf(scB, hB[e], accO[e]);
        }

        if (it + 1 < NIT) {
#pragma unroll
            for (int j = 0; j < 8; ++j) { hA[j] = nA[j]; hB[j] = nB[j]; }
        }
    }

    // ---- reduce over the 16 position-lanes (g-copies identical) ----
#pragma unroll
    for (int m = 1; m < 16; m <<= 1)
#pragma unroll
        for (int e = 0; e < 8; ++e) accO[e] += __shfl_xor(accO[e], m);

    if (l == 0) {
        *reinterpret_cast<float4*>(&outbuf[wave][0]) = make_float4(accO[0], accO[1], accO[2], accO[3]);
        *reinterpret_cast<float4*>(&outbuf[wave][4]) = make_float4(accO[4], accO[5], accO[6], accO[7]);
    }
    __syncthreads();
    if (tid < 16) {
        const int r = tid >> 3, e = tid & 7;
        out[(size_t)(blockIdx.x * 2 + r) * 8 + e] = outbuf[2 * r][e] + outbuf[2 * r + 1][e];
    }
}

extern "C" void kernel_launch(void* const* d_in, const int* in_sizes, int n_in,
                              void* d_out, int out_size, void* d_ws, size_t ws_size,
                              hipStream_t stream) {
    const float* query = (const float*)d_in[0];
    const float* hist  = (const float*)d_in[1];
    const int*   hlen  = (const int*)d_in[2];
    const float* W1    = (const float*)d_in[3];
    const float* b1    = (const float*)d_in[4];
    const float* W2    = (const float*)d_in[5];
    const float* b2    = (const float*)d_in[6];
    const float* W3    = (const float*)d_in[7];
    const float* b3    = (const float*)d_in[8];
    float*       out   = (float*)d_out;

    unsigned short* wsW1 = (unsigned short*)d_ws;          // 4KB
    unsigned short* wsW2 = wsW1 + 4 * 64 * 8;              // 4KB

    prep_kernel<<<1, 256, 0, stream>>>(W1, W2, wsW1, wsW2);
    din3_kernel<<<BB / 2, 256, 0, stream>>>(query, hist, hlen, wsW1, wsW2,
                                            b1, b2, W3, b3, out);
}

// Round 7
// 51.470 us; speedup vs baseline: 1.1302x; 1.1302x over previous
//
#include <hip/hip_runtime.h>
#include <hip/hip_bf16.h>

// B=8192, S=200, E=8, H1=64, H2=32
// att_in = [q, h, q-h, q*h] (32) -> relu(@W1[32,64]+b1) -> relu(@W2[64,32]+b2)
// score = @W3[32,1]+b3 ; mask s<len ; out[b,:] = sum_s score*hist[b,s,:]
// Transposed chain (h1^T = W1^T att^T, h2^T = W2^T relu(h1)^T); wave owns TWO
// batch rows sequentially (amortized setup, long-lived waves, no syncthreads).
#define BB 8192
#define SS 200

typedef __attribute__((ext_vector_type(8))) short short8;   // bf16x8 MFMA frag
typedef __attribute__((ext_vector_type(4))) float f32x4;    // fp32x4 MFMA acc

__device__ __forceinline__ unsigned short f2bf(float f) {
    union { float f; unsigned int u; } v; v.f = f;
    unsigned int r = v.u + 0x7FFFu + ((v.u >> 16) & 1u);    // RNE
    return (unsigned short)(r >> 16);
}
// pack 2 fp32 -> 1 u32 of 2 bf16 (v_cvt_pk_bf16_f32)
__device__ __forceinline__ unsigned int packbf2(float a, float b) {
    union { __hip_bfloat162 h; unsigned int u; } v;
    v.h = __float22bfloat162_rn(make_float2(a, b));
    return v.u;
}

// ---- prep: pack W1 [32,64], W2 [64,32] into per-lane bf16 A-frags (transposed use) ----
// wsW1[(n*64+l)*8+j]        = W1[8g+j][16n+c]      (stage-1' A = W1^T tile n)
// wsW2[((kc*2+n)*64+l)*8+j] = W2[32kc+8g+j][16n+c] (stage-2' A = W2^T tile n, k-chunk kc)
__global__ void prep_kernel(const float* __restrict__ W1, const float* __restrict__ W2,
                            unsigned short* __restrict__ wsW1,
                            unsigned short* __restrict__ wsW2) {
    int t = threadIdx.x;             // 0..255
    int l = t & 63;
    int g = l >> 4, c = l & 15;
    {
        int n = t >> 6;              // 0..3
#pragma unroll
        for (int j = 0; j < 8; ++j)
            wsW1[(n * 64 + l) * 8 + j] = f2bf(W1[(8 * g + j) * 64 + 16 * n + c]);
    }
    {
        int kc = t >> 7, n = (t >> 6) & 1;
#pragma unroll
        for (int j = 0; j < 8; ++j)
            wsW2[((kc * 2 + n) * 64 + l) * 8 + j] = f2bf(W2[(32 * kc + 8 * g + j) * 32 + 16 * n + c]);
    }
}

// ---- main: 4 waves/block; wave w handles rows w and w+4096 ----
__global__ __launch_bounds__(256)
void din4_kernel(const float* __restrict__ query,       // [B,1,8]
                 const float* __restrict__ hist,        // [B,200,8]
                 const int* __restrict__ hlen,          // [B] int32
                 const unsigned short* __restrict__ wsW1,
                 const unsigned short* __restrict__ wsW2,
                 const float* __restrict__ b1,          // [64]
                 const float* __restrict__ b2,          // [32]
                 const float* __restrict__ W3,          // [32]
                 const float* __restrict__ b3,          // [1]
                 float* __restrict__ out)               // [B,1,8]
{
    const int tid  = threadIdx.x;
    const int wave = tid >> 6;
    const int l    = tid & 63;
    const int g    = l >> 4;     // k-block group
    const int c    = l & 15;     // position-within-subtile
    const int wid  = blockIdx.x * 4 + wave;   // 0..4095

    __shared__ unsigned short lds[4][2][1024];   // per-wave h1 dbuf, 16B-slot XOR swizzle

    // ---- one-time per-WAVE setup (amortized over 2 rows / 14 iterations) ----
    // att value for this lane's k-block: v = alpha*q + (beta + gamma*q)*h
    const float alpha = (g == 0 || g == 2) ? 1.0f : 0.0f;
    const float beta  = (g == 1) ? 1.0f : ((g == 2) ? -1.0f : 0.0f);
    const float gamma = (g == 3) ? 1.0f : 0.0f;

    short8 w1f[4];
#pragma unroll
    for (int n = 0; n < 4; ++n)
        w1f[n] = *reinterpret_cast<const short8*>(wsW1 + (n * 64 + l) * 8);
    short8 w2tf[2][2];
#pragma unroll
    for (int kc = 0; kc < 2; ++kc)
#pragma unroll
        for (int n2 = 0; n2 < 2; ++n2)
            w2tf[kc][n2] = *reinterpret_cast<const short8*>(wsW2 + ((kc * 2 + n2) * 64 + l) * 8);

    f32x4 b1c[4];
#pragma unroll
    for (int n = 0; n < 4; ++n)
        b1c[n] = *reinterpret_cast<const f32x4*>(b1 + 16 * n + 4 * g);
    f32x4 b2c[2], W3v[2];
#pragma unroll
    for (int n2 = 0; n2 < 2; ++n2) {
        b2c[n2] = *reinterpret_cast<const f32x4*>(b2 + 16 * n2 + 4 * g);
        W3v[n2] = *reinterpret_cast<const f32x4*>(W3 + 16 * n2 + 4 * g);
    }
    const float b3s = b3[0];

    // LDS offsets (ushort units):
    // write n: c*64 + ((2n + (g>>1)) ^ (c&7))*8 + (g&1)*4   (ds_write_b64)
    // read kc: c*64 + ((4kc + g) ^ (c&7))*8                 (ds_read_b128)
    int woff[4], roff[2];
#pragma unroll
    for (int n = 0; n < 4; ++n)
        woff[n] = c * 64 + (((2 * n + (g >> 1)) ^ (c & 7)) << 3) + ((g & 1) << 2);
#pragma unroll
    for (int kc = 0; kc < 2; ++kc)
        roff[kc] = c * 64 + (((4 * kc + g) ^ (c & 7)) << 3);
    unsigned short* L0 = &lds[wave][0][0];
    unsigned short* L1 = &lds[wave][1][0];

    // ---- row loop: 2 rows per wave ----
#pragma unroll 1
    for (int rr = 0; rr < 2; ++rr) {
        const int brow = wid + rr * 4096;
        const int len  = hlen[brow];

        const float4* qp = reinterpret_cast<const float4*>(query + (size_t)brow * 8);
        float4 qa = qp[0], qb = qp[1];
        float q[8] = {qa.x, qa.y, qa.z, qa.w, qb.x, qb.y, qb.z, qb.w};
        float aq[8], bcv[8];
#pragma unroll
        for (int j = 0; j < 8; ++j) { aq[j] = alpha * q[j]; bcv[j] = beta + gamma * q[j]; }

        const float* hrow = hist + (size_t)brow * SS * 8;
        float accO[8];
#pragma unroll
        for (int e = 0; e < 8; ++e) accO[e] = 0.0f;

        // preload subtiles 0,1
        float hA[8], hB[8];
        {
            const float4* pa = reinterpret_cast<const float4*>(hrow + (size_t)min(c, SS - 1) * 8);
            const float4* pb = reinterpret_cast<const float4*>(hrow + (size_t)min(16 + c, SS - 1) * 8);
            float4 a0 = pa[0], a1 = pa[1], b0 = pb[0], b1_ = pb[1];
            hA[0]=a0.x; hA[1]=a0.y; hA[2]=a0.z; hA[3]=a0.w; hA[4]=a1.x; hA[5]=a1.y; hA[6]=a1.z; hA[7]=a1.w;
            hB[0]=b0.x; hB[1]=b0.y; hB[2]=b0.z; hB[3]=b0.w; hB[4]=b1_.x; hB[5]=b1_.y; hB[6]=b1_.z; hB[7]=b1_.w;
        }

#pragma unroll 1
        for (int it = 0; it < 7; ++it) {   // subtiles 2it, 2it+1
            // ---- prefetch next pair ----
            float nA[8], nB[8];
            if (it < 6) {
                const float4* pa = reinterpret_cast<const float4*>(hrow + (size_t)min(32 * it + 32 + c, SS - 1) * 8);
                const float4* pb = reinterpret_cast<const float4*>(hrow + (size_t)min(32 * it + 48 + c, SS - 1) * 8);
                float4 a0 = pa[0], a1 = pa[1], b0 = pb[0], b1_ = pb[1];
                nA[0]=a0.x; nA[1]=a0.y; nA[2]=a0.z; nA[3]=a0.w; nA[4]=a1.x; nA[5]=a1.y; nA[6]=a1.z; nA[7]=a1.w;
                nB[0]=b0.x; nB[1]=b0.y; nB[2]=b0.z; nB[3]=b0.w; nB[4]=b1_.x; nB[5]=b1_.y; nB[6]=b1_.z; nB[7]=b1_.w;
            }

            // ---- B-role frags (att^T) ----
            union { unsigned int u[4]; short8 s; } ufA, ufB;
#pragma unroll
            for (int m = 0; m < 4; ++m) {
                ufA.u[m] = packbf2(fmaf(bcv[2*m], hA[2*m], aq[2*m]), fmaf(bcv[2*m+1], hA[2*m+1], aq[2*m+1]));
                ufB.u[m] = packbf2(fmaf(bcv[2*m], hB[2*m], aq[2*m]), fmaf(bcv[2*m+1], hB[2*m+1], aq[2*m+1]));
            }

            // ---- stage 1': h1^T = W1^T @ att^T (bias as C-operand) ----
            f32x4 a1A[4], a1B[4];
#pragma unroll
            for (int n = 0; n < 4; ++n) {
                a1A[n] = __builtin_amdgcn_mfma_f32_16x16x32_bf16(w1f[n], ufA.s, b1c[n], 0, 0, 0);
                a1B[n] = __builtin_amdgcn_mfma_f32_16x16x32_bf16(w1f[n], ufB.s, b1c[n], 0, 0, 0);
            }

            // ---- relu + pack + swizzled b64 writes ----
#pragma unroll
            for (int n = 0; n < 4; ++n) {
                uint2 vA = make_uint2(packbf2(fmaxf(a1A[n][0], 0.f), fmaxf(a1A[n][1], 0.f)),
                                      packbf2(fmaxf(a1A[n][2], 0.f), fmaxf(a1A[n][3], 0.f)));
                uint2 vB = make_uint2(packbf2(fmaxf(a1B[n][0], 0.f), fmaxf(a1B[n][1], 0.f)),
                                      packbf2(fmaxf(a1B[n][2], 0.f), fmaxf(a1B[n][3], 0.f)));
                *reinterpret_cast<uint2*>(L0 + woff[n]) = vA;
                *reinterpret_cast<uint2*>(L1 + woff[n]) = vB;
            }

            // Same-wave LDS ops execute in order at the DS unit; only stop the
            // compiler from sinking the writes past the reads.
            asm volatile("" ::: "memory");

            short8 hbA[2], hbB[2];
#pragma unroll
            for (int kc = 0; kc < 2; ++kc) {
                hbA[kc] = *reinterpret_cast<const short8*>(L0 + roff[kc]);
                hbB[kc] = *reinterpret_cast<const short8*>(L1 + roff[kc]);
            }

            // ---- stage 2': h2^T = W2^T @ relu(h1)^T ----
            f32x4 a2A[2], a2B[2];
#pragma unroll
            for (int n2 = 0; n2 < 2; ++n2) {
                a2A[n2] = __builtin_amdgcn_mfma_f32_16x16x32_bf16(w2tf[0][n2], hbA[0], b2c[n2], 0, 0, 0);
                a2A[n2] = __builtin_amdgcn_mfma_f32_16x16x32_bf16(w2tf[1][n2], hbA[1], a2A[n2], 0, 0, 0);
                a2B[n2] = __builtin_amdgcn_mfma_f32_16x16x32_bf16(w2tf[0][n2], hbB[0], b2c[n2], 0, 0, 0);
                a2B[n2] = __builtin_amdgcn_mfma_f32_16x16x32_bf16(w2tf[1][n2], hbB[1], a2B[n2], 0, 0, 0);
            }

            // ---- stage 3: lane-local dot with W3, 2-hop butterfly over g-copies ----
            float pA = 0.f, pB = 0.f;
#pragma unroll
            for (int n2 = 0; n2 < 2; ++n2)
#pragma unroll
                for (int r = 0; r < 4; ++r) {
                    pA = fmaf(fmaxf(a2A[n2][r], 0.f), W3v[n2][r], pA);
                    pB = fmaf(fmaxf(a2B[n2][r], 0.f), W3v[n2][r], pB);
                }
            pA += __shfl_xor(pA, 16); pA += __shfl_xor(pA, 32);
            pB += __shfl_xor(pB, 16); pB += __shfl_xor(pB, 32);

            const int s0 = 32 * it;
            float scA = (s0 + c      < len) ? (pA + b3s) : 0.0f;
            float scB = (s0 + 16 + c < len) ? (pB + b3s) : 0.0f;

            // ---- pooling (fp32 hist already in the right lanes) ----
#pragma unroll
            for (int e = 0; e < 8; ++e) {
                accO[e] = fmaf(scA, hA[e], accO[e]);
                accO[e] = fmaf(scB, hB[e], accO[e]);
            }

            if (it < 6) {
#pragma unroll
                for (int j = 0; j < 8; ++j) { hA[j] = nA[j]; hB[j] = nB[j]; }
            }
        }

        // ---- reduce over the 16 position-lanes (g-copies identical) ----
#pragma unroll
        for (int m = 1; m < 16; m <<= 1)
#pragma unroll
            for (int e = 0; e < 8; ++e) accO[e] += __shfl_xor(accO[e], m);

        if (l == 0) {
            float4* op = reinterpret_cast<float4*>(out + (size_t)brow * 8);
            op[0] = make_float4(accO[0], accO[1], accO[2], accO[3]);
            op[1] = make_float4(accO[4], accO[5], accO[6], accO[7]);
        }
    }
}

extern "C" void kernel_launch(void* const* d_in, const int* in_sizes, int n_in,
                              void* d_out, int out_size, void* d_ws, size_t ws_size,
                              hipStream_t stream) {
    const float* query = (const float*)d_in[0];
    const float* hist  = (const float*)d_in[1];
    const int*   hlen  = (const int*)d_in[2];
    const float* W1    = (const float*)d_in[3];
    const float* b1    = (const float*)d_in[4];
    const float* W2    = (const float*)d_in[5];
    const float* b2    = (const float*)d_in[6];
    const float* W3    = (const float*)d_in[7];
    const float* b3    = (const float*)d_in[8];
    float*       out   = (float*)d_out;

    unsigned short* wsW1 = (unsigned short*)d_ws;          // 4KB
    unsigned short* wsW2 = wsW1 + 4 * 64 * 8;              // 4KB

    prep_kernel<<<1, 256, 0, stream>>>(W1, W2, wsW1, wsW2);
    din4_kernel<<<BB / 8, 256, 0, stream>>>(query, hist, hlen, wsW1, wsW2,
                                            b1, b2, W3, b3, out);
}

// Round 8
// 45.927 us; speedup vs baseline: 1.2665x; 1.1207x over previous
//
#include <hip/hip_runtime.h>
#include <hip/hip_bf16.h>

// B=8192, S=200, E=8, H1=64, H2=32
// att_in = [q, h, q-h, q*h] (32) -> relu(@W1[32,64]+b1) -> relu(@W2[64,32]+b2)
// score = @W3[32,1]+b3 ; mask s<len ; out[b,:] = sum_s score*hist[b,s,:]
// Transposed chain (h1^T = W1^T att^T, h2^T = W2^T relu(h1)^T), wave-per-row,
// depth-2 software pipeline: front(t+1) = {att,MFMA1,pack,LDS-write} issues
// before back(t) = {LDS-read,MFMA2,score,pool} -> two independent streams/iter.
#define BB 8192
#define SS 200

typedef __attribute__((ext_vector_type(8))) short short8;   // bf16x8 MFMA frag
typedef __attribute__((ext_vector_type(4))) float f32x4;    // fp32x4 MFMA acc

__device__ __forceinline__ unsigned short f2bf(float f) {
    union { float f; unsigned int u; } v; v.f = f;
    unsigned int r = v.u + 0x7FFFu + ((v.u >> 16) & 1u);    // RNE
    return (unsigned short)(r >> 16);
}
// pack 2 fp32 -> 1 u32 of 2 bf16
__device__ __forceinline__ unsigned int packbf2(float a, float b) {
    union { __hip_bfloat162 h; unsigned int u; } v;
    v.h = __float22bfloat162_rn(make_float2(a, b));
    return v.u;
}

// ---- prep: pack W1 [32,64], W2 [64,32] into per-lane bf16 A-frags (transposed use) ----
// wsW1[(n*64+l)*8+j]        = W1[8g+j][16n+c]      (stage-1' A = W1^T tile n)
// wsW2[((kc*2+n)*64+l)*8+j] = W2[32kc+8g+j][16n+c] (stage-2' A = W2^T tile n, k-chunk kc)
__global__ void prep_kernel(const float* __restrict__ W1, const float* __restrict__ W2,
                            unsigned short* __restrict__ wsW1,
                            unsigned short* __restrict__ wsW2) {
    int t = threadIdx.x;             // 0..255
    int l = t & 63;
    int g = l >> 4, c = l & 15;
    {
        int n = t >> 6;              // 0..3
#pragma unroll
        for (int j = 0; j < 8; ++j)
            wsW1[(n * 64 + l) * 8 + j] = f2bf(W1[(8 * g + j) * 64 + 16 * n + c]);
    }
    {
        int kc = t >> 7, n = (t >> 6) & 1;
#pragma unroll
        for (int j = 0; j < 8; ++j)
            wsW2[((kc * 2 + n) * 64 + l) * 8 + j] = f2bf(W2[(32 * kc + 8 * g + j) * 32 + 16 * n + c]);
    }
}

// ---- main: 4 waves/block; wave owns one batch row; depth-2 pipeline over 13 subtiles ----
__global__ __launch_bounds__(256)
void din5_kernel(const float* __restrict__ query,       // [B,1,8]
                 const float* __restrict__ hist,        // [B,200,8]
                 const int* __restrict__ hlen,          // [B] int32
                 const unsigned short* __restrict__ wsW1,
                 const unsigned short* __restrict__ wsW2,
                 const float* __restrict__ b1,          // [64]
                 const float* __restrict__ b2,          // [32]
                 const float* __restrict__ W3,          // [32]
                 const float* __restrict__ b3,          // [1]
                 float* __restrict__ out)               // [B,1,8]
{
    const int tid  = threadIdx.x;
    const int wave = tid >> 6;
    const int l    = tid & 63;
    const int g    = l >> 4;     // k-block group
    const int c    = l & 15;     // position-within-subtile
    const int brow = blockIdx.x * 4 + wave;

    __shared__ unsigned short lds[4][2][1024];   // per-wave pipeline dbuf, 16B-slot XOR swizzle

    const int len = hlen[brow];

    // ---- per-wave setup ----
    const float alpha = (g == 0 || g == 2) ? 1.0f : 0.0f;
    const float beta  = (g == 1) ? 1.0f : ((g == 2) ? -1.0f : 0.0f);
    const float gamma = (g == 3) ? 1.0f : 0.0f;

    short8 w1f[4];
#pragma unroll
    for (int n = 0; n < 4; ++n)
        w1f[n] = *reinterpret_cast<const short8*>(wsW1 + (n * 64 + l) * 8);
    short8 w2tf[2][2];
#pragma unroll
    for (int kc = 0; kc < 2; ++kc)
#pragma unroll
        for (int n2 = 0; n2 < 2; ++n2)
            w2tf[kc][n2] = *reinterpret_cast<const short8*>(wsW2 + ((kc * 2 + n2) * 64 + l) * 8);

    f32x4 b1c[4];
#pragma unroll
    for (int n = 0; n < 4; ++n)
        b1c[n] = *reinterpret_cast<const f32x4*>(b1 + 16 * n + 4 * g);
    f32x4 b2c[2], W3v[2];
#pragma unroll
    for (int n2 = 0; n2 < 2; ++n2) {
        b2c[n2] = *reinterpret_cast<const f32x4*>(b2 + 16 * n2 + 4 * g);
        W3v[n2] = *reinterpret_cast<const f32x4*>(W3 + 16 * n2 + 4 * g);
    }
    const float b3s = b3[0];

    const float4* qp = reinterpret_cast<const float4*>(query + (size_t)brow * 8);
    float4 qa = qp[0], qb = qp[1];
    float q[8] = {qa.x, qa.y, qa.z, qa.w, qb.x, qb.y, qb.z, qb.w};
    float aq[8], bcv[8];
#pragma unroll
    for (int j = 0; j < 8; ++j) { aq[j] = alpha * q[j]; bcv[j] = beta + gamma * q[j]; }

    // LDS offsets (ushort units):
    // write n: c*64 + ((2n + (g>>1)) ^ (c&7))*8 + (g&1)*4   (ds_write_b64)
    // read kc: c*64 + ((4kc + g) ^ (c&7))*8                 (ds_read_b128)
    int woff[4], roff[2];
#pragma unroll
    for (int n = 0; n < 4; ++n)
        woff[n] = c * 64 + (((2 * n + (g >> 1)) ^ (c & 7)) << 3) + ((g & 1) << 2);
#pragma unroll
    for (int kc = 0; kc < 2; ++kc)
        roff[kc] = c * 64 + (((4 * kc + g) ^ (c & 7)) << 3);

    const float* hrow = hist + (size_t)brow * SS * 8;
    float accO[8];
#pragma unroll
    for (int e = 0; e < 8; ++e) accO[e] = 0.0f;

    float hreg[3][8];   // h of subtiles it, it+1, it+2 (rotating; statically indexed)

    auto loadH = [&](int x, float* h) {
        const float4* p = reinterpret_cast<const float4*>(hrow + (size_t)min(16 * x + c, SS - 1) * 8);
        float4 v0 = p[0], v1 = p[1];
        h[0]=v0.x; h[1]=v0.y; h[2]=v0.z; h[3]=v0.w;
        h[4]=v1.x; h[5]=v1.y; h[6]=v1.z; h[7]=v1.w;
    };

    // FRONT: att frag -> stage-1' MFMA -> relu+pack -> swizzled LDS write
    auto front = [&](const float* h, int buf) {
        union { unsigned int u[4]; short8 s; } uf;
#pragma unroll
        for (int m = 0; m < 4; ++m)
            uf.u[m] = packbf2(fmaf(bcv[2*m], h[2*m], aq[2*m]),
                              fmaf(bcv[2*m+1], h[2*m+1], aq[2*m+1]));
        f32x4 a1[4];
#pragma unroll
        for (int n = 0; n < 4; ++n)
            a1[n] = __builtin_amdgcn_mfma_f32_16x16x32_bf16(w1f[n], uf.s, b1c[n], 0, 0, 0);
        unsigned short* L = &lds[wave][buf][0];
#pragma unroll
        for (int n = 0; n < 4; ++n) {
            uint2 v = make_uint2(packbf2(fmaxf(a1[n][0], 0.f), fmaxf(a1[n][1], 0.f)),
                                 packbf2(fmaxf(a1[n][2], 0.f), fmaxf(a1[n][3], 0.f)));
            *reinterpret_cast<uint2*>(L + woff[n]) = v;
        }
    };

    // BACK: LDS read -> stage-2' MFMA -> W3 dot -> mask -> pool
    auto back = [&](int x, const float* h, int buf) {
        asm volatile("" ::: "memory");   // keep writes(front) above reads(back) in program order
        const unsigned short* L = &lds[wave][buf][0];
        short8 hb0 = *reinterpret_cast<const short8*>(L + roff[0]);
        short8 hb1 = *reinterpret_cast<const short8*>(L + roff[1]);
        f32x4 a2[2];
#pragma unroll
        for (int n2 = 0; n2 < 2; ++n2) {
            a2[n2] = __builtin_amdgcn_mfma_f32_16x16x32_bf16(w2tf[0][n2], hb0, b2c[n2], 0, 0, 0);
            a2[n2] = __builtin_amdgcn_mfma_f32_16x16x32_bf16(w2tf[1][n2], hb1, a2[n2], 0, 0, 0);
        }
        float p = 0.f;
#pragma unroll
        for (int n2 = 0; n2 < 2; ++n2)
#pragma unroll
            for (int r = 0; r < 4; ++r)
                p = fmaf(fmaxf(a2[n2][r], 0.f), W3v[n2][r], p);
        p += __shfl_xor(p, 16); p += __shfl_xor(p, 32);
        float sc = (16 * x + c < len) ? (p + b3s) : 0.0f;
#pragma unroll
        for (int e = 0; e < 8; ++e) accO[e] = fmaf(sc, h[e], accO[e]);
    };

    // ---- pipeline: front(t+1) before back(t) ----
    loadH(0, hreg[0]);
    loadH(1, hreg[1]);
    front(hreg[0], 0);
#pragma unroll
    for (int it = 0; it < 12; ++it) {
        if (it + 2 < 13) loadH(it + 2, hreg[(it + 2) % 3]);
        front(hreg[(it + 1) % 3], (it + 1) & 1);
        back(it, hreg[it % 3], it & 1);
    }
    back(12, hreg[0], 0);   // 12%3==0, 12&1==0

    // ---- reduce over the 16 position-lanes (g-copies identical) ----
#pragma unroll
    for (int m = 1; m < 16; m <<= 1)
#pragma unroll
        for (int e = 0; e < 8; ++e) accO[e] += __shfl_xor(accO[e], m);

    if (l == 0) {
        float4* op = reinterpret_cast<float4*>(out + (size_t)brow * 8);
        op[0] = make_float4(accO[0], accO[1], accO[2], accO[3]);
        op[1] = make_float4(accO[4], accO[5], accO[6], accO[7]);
    }
}

extern "C" void kernel_launch(void* const* d_in, const int* in_sizes, int n_in,
                              void* d_out, int out_size, void* d_ws, size_t ws_size,
                              hipStream_t stream) {
    const float* query = (const float*)d_in[0];
    const float* hist  = (const float*)d_in[1];
    const int*   hlen  = (const int*)d_in[2];
    const float* W1    = (const float*)d_in[3];
    const float* b1    = (const float*)d_in[4];
    const float* W2    = (const float*)d_in[5];
    const float* b2    = (const float*)d_in[6];
    const float* W3    = (const float*)d_in[7];
    const float* b3    = (const float*)d_in[8];
    float*       out   = (float*)d_out;

    unsigned short* wsW1 = (unsigned short*)d_ws;          // 4KB
    unsigned short* wsW2 = wsW1 + 4 * 64 * 8;              // 4KB

    prep_kernel<<<1, 256, 0, stream>>>(W1, W2, wsW1, wsW2);
    din5_kernel<<<BB / 4, 256, 0, stream>>>(query, hist, hlen, wsW1, wsW2,
                                            b1, b2, W3, b3, out);
}

// Round 9
// 44.877 us; speedup vs baseline: 1.2962x; 1.0234x over previous
//
#include <hip/hip_runtime.h>
#include <hip/hip_bf16.h>

// B=8192, S=200, E=8, H1=64, H2=32
// att_in = [q, h, q-h, q*h] (32) -> relu(@W1[32,64]+b1) -> relu(@W2[64,32]+b2)
// score = @W3[32,1]+b3 ; mask s<len ; out[b,:] = sum_s score*hist[b,s,:]
// Transposed chain (h1^T = W1^T att^T, h2^T = W2^T relu(h1)^T), wave-per-row,
// depth-2 front/back software pipeline + depth-3 global prefetch (4 h buffers).
#define BB 8192
#define SS 200

typedef __attribute__((ext_vector_type(8))) short short8;   // bf16x8 MFMA frag
typedef __attribute__((ext_vector_type(4))) float f32x4;    // fp32x4 MFMA acc

__device__ __forceinline__ unsigned short f2bf(float f) {
    union { float f; unsigned int u; } v; v.f = f;
    unsigned int r = v.u + 0x7FFFu + ((v.u >> 16) & 1u);    // RNE
    return (unsigned short)(r >> 16);
}
// pack 2 fp32 -> 1 u32 of 2 bf16
__device__ __forceinline__ unsigned int packbf2(float a, float b) {
    union { __hip_bfloat162 h; unsigned int u; } v;
    v.h = __float22bfloat162_rn(make_float2(a, b));
    return v.u;
}

// ---- prep: pack W1 [32,64], W2 [64,32] into per-lane bf16 A-frags (transposed use) ----
// wsW1[(n*64+l)*8+j]        = W1[8g+j][16n+c]      (stage-1' A = W1^T tile n)
// wsW2[((kc*2+n)*64+l)*8+j] = W2[32kc+8g+j][16n+c] (stage-2' A = W2^T tile n, k-chunk kc)
__global__ void prep_kernel(const float* __restrict__ W1, const float* __restrict__ W2,
                            unsigned short* __restrict__ wsW1,
                            unsigned short* __restrict__ wsW2) {
    int t = threadIdx.x;             // 0..255
    int l = t & 63;
    int g = l >> 4, c = l & 15;
    {
        int n = t >> 6;              // 0..3
#pragma unroll
        for (int j = 0; j < 8; ++j)
            wsW1[(n * 64 + l) * 8 + j] = f2bf(W1[(8 * g + j) * 64 + 16 * n + c]);
    }
    {
        int kc = t >> 7, n = (t >> 6) & 1;
#pragma unroll
        for (int j = 0; j < 8; ++j)
            wsW2[((kc * 2 + n) * 64 + l) * 8 + j] = f2bf(W2[(32 * kc + 8 * g + j) * 32 + 16 * n + c]);
    }
}

// ---- main: 4 waves/block; wave owns one batch row; 13 subtiles, fully unrolled ----
__global__ __launch_bounds__(256)
void din6_kernel(const float* __restrict__ query,       // [B,1,8]
                 const float* __restrict__ hist,        // [B,200,8]
                 const int* __restrict__ hlen,          // [B] int32
                 const unsigned short* __restrict__ wsW1,
                 const unsigned short* __restrict__ wsW2,
                 const float* __restrict__ b1,          // [64]
                 const float* __restrict__ b2,          // [32]
                 const float* __restrict__ W3,          // [32]
                 const float* __restrict__ b3,          // [1]
                 float* __restrict__ out)               // [B,1,8]
{
    const int tid  = threadIdx.x;
    const int wave = tid >> 6;
    const int l    = tid & 63;
    const int g    = l >> 4;     // k-block group
    const int c    = l & 15;     // position-within-subtile
    const int brow = blockIdx.x * 4 + wave;

    __shared__ unsigned short lds[4][2][1024];   // per-wave pipeline dbuf, 16B-slot XOR swizzle

    const int len = hlen[brow];

    // ---- per-wave setup ----
    const float alpha = (g == 0 || g == 2) ? 1.0f : 0.0f;
    const float beta  = (g == 1) ? 1.0f : ((g == 2) ? -1.0f : 0.0f);
    const float gamma = (g == 3) ? 1.0f : 0.0f;

    short8 w1f[4];
#pragma unroll
    for (int n = 0; n < 4; ++n)
        w1f[n] = *reinterpret_cast<const short8*>(wsW1 + (n * 64 + l) * 8);
    short8 w2tf[2][2];
#pragma unroll
    for (int kc = 0; kc < 2; ++kc)
#pragma unroll
        for (int n2 = 0; n2 < 2; ++n2)
            w2tf[kc][n2] = *reinterpret_cast<const short8*>(wsW2 + ((kc * 2 + n2) * 64 + l) * 8);

    f32x4 b1c[4];
#pragma unroll
    for (int n = 0; n < 4; ++n)
        b1c[n] = *reinterpret_cast<const f32x4*>(b1 + 16 * n + 4 * g);
    f32x4 b2c[2], W3v[2];
#pragma unroll
    for (int n2 = 0; n2 < 2; ++n2) {
        b2c[n2] = *reinterpret_cast<const f32x4*>(b2 + 16 * n2 + 4 * g);
        W3v[n2] = *reinterpret_cast<const f32x4*>(W3 + 16 * n2 + 4 * g);
    }
    const float b3s = b3[0];

    const float4* qp = reinterpret_cast<const float4*>(query + (size_t)brow * 8);
    float4 qa = qp[0], qb = qp[1];
    float q[8] = {qa.x, qa.y, qa.z, qa.w, qb.x, qb.y, qb.z, qb.w};
    float aq[8], bcv[8];
#pragma unroll
    for (int j = 0; j < 8; ++j) { aq[j] = alpha * q[j]; bcv[j] = beta + gamma * q[j]; }

    // LDS offsets (ushort units):
    // write n: c*64 + ((2n + (g>>1)) ^ (c&7))*8 + (g&1)*4   (ds_write_b64)
    // read kc: c*64 + ((4kc + g) ^ (c&7))*8                 (ds_read_b128)
    int woff[4], roff[2];
#pragma unroll
    for (int n = 0; n < 4; ++n)
        woff[n] = c * 64 + (((2 * n + (g >> 1)) ^ (c & 7)) << 3) + ((g & 1) << 2);
#pragma unroll
    for (int kc = 0; kc < 2; ++kc)
        roff[kc] = c * 64 + (((4 * kc + g) ^ (c & 7)) << 3);

    const float* hrow = hist + (size_t)brow * SS * 8;
    float accO[8];
#pragma unroll
    for (int e = 0; e < 8; ++e) accO[e] = 0.0f;

    float hreg[4][8];   // h of subtiles t..t+3 (rotating, statically indexed)

    auto loadH = [&](int x, float* h) {
        const float4* p = reinterpret_cast<const float4*>(hrow + (size_t)min(16 * x + c, SS - 1) * 8);
        float4 v0 = p[0], v1 = p[1];
        h[0]=v0.x; h[1]=v0.y; h[2]=v0.z; h[3]=v0.w;
        h[4]=v1.x; h[5]=v1.y; h[6]=v1.z; h[7]=v1.w;
    };

    // FRONT: att frag -> stage-1' MFMA -> relu+pack -> swizzled LDS write
    auto front = [&](const float* h, int buf) {
        union { unsigned int u[4]; short8 s; } uf;
#pragma unroll
        for (int m = 0; m < 4; ++m)
            uf.u[m] = packbf2(fmaf(bcv[2*m], h[2*m], aq[2*m]),
                              fmaf(bcv[2*m+1], h[2*m+1], aq[2*m+1]));
        f32x4 a1[4];
#pragma unroll
        for (int n = 0; n < 4; ++n)
            a1[n] = __builtin_amdgcn_mfma_f32_16x16x32_bf16(w1f[n], uf.s, b1c[n], 0, 0, 0);
        unsigned short* L = &lds[wave][buf][0];
#pragma unroll
        for (int n = 0; n < 4; ++n) {
            uint2 v = make_uint2(packbf2(fmaxf(a1[n][0], 0.f), fmaxf(a1[n][1], 0.f)),
                                 packbf2(fmaxf(a1[n][2], 0.f), fmaxf(a1[n][3], 0.f)));
            *reinterpret_cast<uint2*>(L + woff[n]) = v;
        }
    };

    // BACK: LDS read -> stage-2' MFMA -> W3 dot -> mask -> pool
    auto back = [&](int x, const float* h, int buf) {
        asm volatile("" ::: "memory");   // keep writes(front) above reads(back) in program order
        const unsigned short* L = &lds[wave][buf][0];
        short8 hb0 = *reinterpret_cast<const short8*>(L + roff[0]);
        short8 hb1 = *reinterpret_cast<const short8*>(L + roff[1]);
        f32x4 a2[2];
#pragma unroll
        for (int n2 = 0; n2 < 2; ++n2) {
            a2[n2] = __builtin_amdgcn_mfma_f32_16x16x32_bf16(w2tf[0][n2], hb0, b2c[n2], 0, 0, 0);
            a2[n2] = __builtin_amdgcn_mfma_f32_16x16x32_bf16(w2tf[1][n2], hb1, a2[n2], 0, 0, 0);
        }
        float p = 0.f;
#pragma unroll
        for (int n2 = 0; n2 < 2; ++n2)
#pragma unroll
            for (int r = 0; r < 4; ++r)
                p = fmaf(fmaxf(a2[n2][r], 0.f), W3v[n2][r], p);
        p += __shfl_xor(p, 16); p += __shfl_xor(p, 32);
        float sc = (16 * x + c < len) ? (p + b3s) : 0.0f;
#pragma unroll
        for (int e = 0; e < 8; ++e) accO[e] = fmaf(sc, h[e], accO[e]);
    };

    // ---- pipeline: load(t+3) | front(t+1) | back(t) ----
    loadH(0, hreg[0]);
    loadH(1, hreg[1]);
    loadH(2, hreg[2]);
    front(hreg[0], 0);
#pragma unroll
    for (int it = 0; it < 12; ++it) {
        if (it + 3 < 13) loadH(it + 3, hreg[(it + 3) & 3]);  // slot (it-1)&3 is dead
        front(hreg[(it + 1) & 3], (it + 1) & 1);
        back(it, hreg[it & 3], it & 1);
    }
    back(12, hreg[12 & 3], 0);

    // ---- reduce over the 16 position-lanes (g-copies identical) ----
#pragma unroll
    for (int m = 1; m < 16; m <<= 1)
#pragma unroll
        for (int e = 0; e < 8; ++e) accO[e] += __shfl_xor(accO[e], m);

    if (l == 0) {
        float4* op = reinterpret_cast<float4*>(out + (size_t)brow * 8);
        op[0] = make_float4(accO[0], accO[1], accO[2], accO[3]);
        op[1] = make_float4(accO[4], accO[5], accO[6], accO[7]);
    }
}

extern "C" void kernel_launch(void* const* d_in, const int* in_sizes, int n_in,
                              void* d_out, int out_size, void* d_ws, size_t ws_size,
                              hipStream_t stream) {
    const float* query = (const float*)d_in[0];
    const float* hist  = (const float*)d_in[1];
    const int*   hlen  = (const int*)d_in[2];
    const float* W1    = (const float*)d_in[3];
    const float* b1    = (const float*)d_in[4];
    const float* W2    = (const float*)d_in[5];
    const float* b2    = (const float*)d_in[6];
    const float* W3    = (const float*)d_in[7];
    const float* b3    = (const float*)d_in[8];
    float*       out   = (float*)d_out;

    unsigned short* wsW1 = (unsigned short*)d_ws;          // 4KB
    unsigned short* wsW2 = wsW1 + 4 * 64 * 8;              // 4KB

    prep_kernel<<<1, 256, 0, stream>>>(W1, W2, wsW1, wsW2);
    din6_kernel<<<BB / 4, 256, 0, stream>>>(query, hist, hlen, wsW1, wsW2,
                                            b1, b2, W3, b3, out);
}